// Round 9
// baseline (389.344 us; speedup 1.0000x reference)
//
#include <hip/hip_runtime.h>
#include <hip/hip_fp16.h>
#include <math.h>

// ---------------------------------------------------------------------------
// SolventGCN round 9: r7 structure (r8 fusion reverted: barrier imbalance ate
// the saved traffic) + three fixes:
//  * phaseA = p1_partition || unscaled layer-0 MFMA GEMM || W pre-swizzle
//    (gemm0 no longer waits on the CSR scan; agg0 applies dinv[src] per edge)
//  * fp16 GEMMs are LDS-free: A-frag = contiguous 16B row slice loaded direct
//    from global; B-frag from pre-swizzled Wz (L1-hot). No barrier, high occ.
//   zero -> phaseA -> p2 -> p3 -> agg0(w) -> gemm1 -> agg1 -> gemm2 -> agg2
//   -> poolDense.   10 launches.
// ---------------------------------------------------------------------------

static inline int cdiv(int a, int b) { return (a + b - 1) / b; }

#define BUCKET_CAP 8192
#define P1_CHUNK   4096

typedef _Float16 v8h __attribute__((ext_vector_type(8)));
typedef float    v4f __attribute__((ext_vector_type(4)));

__global__ void zero_int(int* __restrict__ p, int n) {
    int i = blockIdx.x * blockDim.x + threadIdx.x;
    if (i < n) p[i] = 0;
}

// ---- p1 body: partition edges into buckets (packed) ----
__device__ void p1_body(int bid, const int* __restrict__ c_edge, int Ec,
                        const int* __restrict__ s_edge, int Es,
                        int Nc_pad, int Etot, int nbuck,
                        int* __restrict__ bucket_fill, unsigned* __restrict__ pk,
                        char* smem_) {
    unsigned*       wbuf = (unsigned*)smem_;                  // 16 KB
    unsigned short* bbuf = (unsigned short*)(smem_ + 16384);  // 8 KB
    int*            hist = (int*)(smem_ + 24576);             // 2 KB
    int e0 = bid * P1_CHUNK;
    int n  = Etot - e0;
    if (n > P1_CHUNK) n = P1_CHUNK;
    for (int i = threadIdx.x; i < nbuck; i += 256) hist[i] = 0;
    __syncthreads();
    for (int i = threadIdx.x; i < n; i += 256) {
        int e = e0 + i, src, g;
        if (e < Ec) { src = c_edge[e]; g = c_edge[Ec + e]; }
        else        { int e2 = e - Ec; src = s_edge[e2]; g = Nc_pad + s_edge[Es + e2]; }
        int b   = g >> 9;
        wbuf[i] = ((unsigned)(g & 511) << 17) | (unsigned)src;
        bbuf[i] = (unsigned short)b;
        atomicAdd(&hist[b], 1);
    }
    __syncthreads();
    for (int i = threadIdx.x; i < nbuck; i += 256) {
        int h = hist[i];
        hist[i] = h ? atomicAdd(&bucket_fill[i], h) : 0;
    }
    __syncthreads();
    for (int i = threadIdx.x; i < n; i += 256) {
        int b    = bbuf[i];
        int slot = atomicAdd(&hist[b], 1);
        if (slot < BUCKET_CAP) pk[(size_t)b * BUCKET_CAP + slot] = wbuf[i];
    }
}

// ---- pass 2: exclusive scan of bucket fills ----
__global__ __launch_bounds__(512) void p2_scanbuckets(const int* __restrict__ fill, int nbuck,
                                                      int* __restrict__ basearr,
                                                      int* __restrict__ off_all, int Ntot_pad, int Etot) {
    __shared__ int sh[512];
    int v = (threadIdx.x < nbuck) ? fill[threadIdx.x] : 0;
    sh[threadIdx.x] = v;
    __syncthreads();
    for (int ofs = 1; ofs < 512; ofs <<= 1) {
        int t = (threadIdx.x >= ofs) ? sh[threadIdx.x - ofs] : 0;
        __syncthreads();
        sh[threadIdx.x] += t;
        __syncthreads();
    }
    if (threadIdx.x < nbuck) basearr[threadIdx.x] = sh[threadIdx.x] - v;
    if (threadIdx.x == 0) off_all[Ntot_pad] = Etot;
}

// ---- pass 3: per-bucket CSR build (all per-edge atomics in LDS) ----
__global__ __launch_bounds__(512) void p3_build(const unsigned* __restrict__ pk,
                                                const int* __restrict__ fillarr,
                                                const int* __restrict__ basearr,
                                                int* __restrict__ off_all,
                                                float* __restrict__ dinv,
                                                int* __restrict__ csr) {
    __shared__ int sh[512];
    int b    = blockIdx.x;
    int fill = fillarr[b];
    if (fill > BUCKET_CAP) fill = BUCKET_CAP;
    int base = basearr[b];
    const unsigned* reg = pk + (size_t)b * BUCKET_CAP;
    sh[threadIdx.x] = 0;
    __syncthreads();
    for (int i = threadIdx.x; i < fill; i += 512) atomicAdd(&sh[reg[i] >> 17], 1);
    __syncthreads();
    int cnt = sh[threadIdx.x];
    for (int ofs = 1; ofs < 512; ofs <<= 1) {   // inclusive scan
        int t = (threadIdx.x >= ofs) ? sh[threadIdx.x - ofs] : 0;
        __syncthreads();
        sh[threadIdx.x] += t;
        __syncthreads();
    }
    int excl = sh[threadIdx.x] - cnt;
    int node = b * 512 + threadIdx.x;           // padded-global id
    off_all[node] = base + excl;
    dinv[node]    = rsqrtf((float)(cnt + 1));   // +1 self-loop
    __syncthreads();
    sh[threadIdx.x] = excl;   // cursor for CSR scatter
    __syncthreads();
    for (int i = threadIdx.x; i < fill; i += 512) {
        unsigned w    = reg[i];
        int      slot = atomicAdd(&sh[w >> 17], 1);
        csr[base + slot] = (int)(w & 0x1FFFFu);
    }
}

// ---- W pre-swizzle body: Wz[idx][8] = B-fragment order ----
__device__ void prepW_body(const float* __restrict__ W, int M, _Float16* __restrict__ out) {
    int NT = M / 16, KS = M / 32;
    int WENT = NT * KS * 64;
    for (int idx = threadIdx.x; idx < WENT; idx += 256) {
        int ln = idx & 63, rest = idx >> 6;
        int ks = rest % KS, ntl = rest / KS;
        int kbase = ks * 32 + (ln >> 4) * 8;
        int col   = ntl * 16 + (ln & 15);
        union { float4 f4; _Float16 h[8]; } u;
#pragma unroll
        for (int j = 0; j < 8; ++j) u.h[j] = (_Float16)W[(kbase + j) * M + col];
        *(float4*)(out + idx * 8) = u.f4;
    }
}

// ---- layer-0 MFMA GEMM (fp32 in, LDS-staged, optional dinv scale) ----
template <int K, int M>
__device__ void gemm_mfma_f32(int bid, const float* __restrict__ X, const float* __restrict__ W,
                              const float* __restrict__ dinv, __half* __restrict__ H, int N,
                              char* smem_) {
    constexpr int RB = 64, KP = K + 8, NT = M / 16, KS = K / 32;
    _Float16* Xh = (_Float16*)smem_;           // [RB][KP]
    _Float16* Wz = Xh + RB * KP;               // [NT*KS*64][8]
    const int t    = threadIdx.x;
    const int row0 = bid * RB;

    constexpr int WENT = NT * KS * 64;
    for (int idx = t; idx < WENT; idx += 256) {
        int lane = idx & 63, rest = idx >> 6;
        int ks = rest % KS, ntl = rest / KS;
        int kbase = ks * 32 + (lane >> 4) * 8;
        int col   = ntl * 16 + (lane & 15);
        union { float4 f4; _Float16 h[8]; } u;
#pragma unroll
        for (int j = 0; j < 8; ++j) u.h[j] = (_Float16)W[(kbase + j) * M + col];
        *(float4*)(Wz + idx * 8) = u.f4;
    }
    constexpr int NI = RB * K / 4;
    for (int idx = t; idx < NI; idx += 256) {
        int row = idx / (K / 4), k4 = idx % (K / 4);
        int gr = row0 + row;
        float4 v = make_float4(0.f, 0.f, 0.f, 0.f);
        if (gr < N) v = *(const float4*)(X + (size_t)gr * K + k4 * 4);
        union { float2 f2; _Float16 h[4]; } u;
        u.h[0] = (_Float16)v.x; u.h[1] = (_Float16)v.y;
        u.h[2] = (_Float16)v.z; u.h[3] = (_Float16)v.w;
        *(float2*)(Xh + row * KP + k4 * 4) = u.f2;
    }
    __syncthreads();

    const int wave = t >> 6, lane = t & 63;
    const int quad = lane >> 4, nl = lane & 15;
    const int rowA = wave * 16 + nl;

    v4f acc[NT];
#pragma unroll
    for (int i = 0; i < NT; ++i) acc[i] = (v4f){0.f, 0.f, 0.f, 0.f};
#pragma unroll
    for (int ks = 0; ks < KS; ++ks) {
        v8h a = *(const v8h*)(Xh + rowA * KP + ks * 32 + quad * 8);
#pragma unroll
        for (int ntl = 0; ntl < NT; ++ntl) {
            v8h b = *(const v8h*)(Wz + ((ntl * KS + ks) * 64 + lane) * 8);
            acc[ntl] = __builtin_amdgcn_mfma_f32_16x16x32_f16(a, b, acc[ntl], 0, 0, 0);
        }
    }
#pragma unroll
    for (int r = 0; r < 4; ++r) {
        int gr = row0 + wave * 16 + quad * 4 + r;
        if (gr < N) {
            float dv = dinv ? dinv[gr] : 1.0f;
#pragma unroll
            for (int ntl = 0; ntl < NT; ++ntl)
                H[(size_t)gr * M + ntl * 16 + nl] = __float2half(acc[ntl][r] * dv);
        }
    }
}

// ---- fp16 square GEMM, LDS-free: A direct 16B row slices, B from Wz ----
template <int M>
__device__ void gemm_direct(int bid, const __half* __restrict__ X,
                            const _Float16* __restrict__ Wz,
                            const float* __restrict__ dinv, __half* __restrict__ H, int N) {
    constexpr int NT = M / 16, KS = M / 32;
    const int t = threadIdx.x, wave = t >> 6, lane = t & 63;
    const int quad = lane >> 4, nl = lane & 15;
    const int row0 = bid * 64;
    int rowA = row0 + wave * 16 + nl;
    if (rowA >= N) rowA = N - 1;               // clamped read; store is masked
    const _Float16* Xp = (const _Float16*)X;

    v4f acc[NT];
#pragma unroll
    for (int i = 0; i < NT; ++i) acc[i] = (v4f){0.f, 0.f, 0.f, 0.f};
#pragma unroll
    for (int ks = 0; ks < KS; ++ks) {
        v8h a = *(const v8h*)(Xp + (size_t)rowA * M + ks * 32 + quad * 8);
#pragma unroll
        for (int ntl = 0; ntl < NT; ++ntl) {
            v8h b = *(const v8h*)(Wz + ((ntl * KS + ks) * 64 + lane) * 8);
            acc[ntl] = __builtin_amdgcn_mfma_f32_16x16x32_f16(a, b, acc[ntl], 0, 0, 0);
        }
    }
#pragma unroll
    for (int r = 0; r < 4; ++r) {
        int gr = row0 + wave * 16 + quad * 4 + r;
        if (gr < N) {
            float dv = dinv[gr];
#pragma unroll
            for (int ntl = 0; ntl < NT; ++ntl)
                H[(size_t)gr * M + ntl * 16 + nl] = __float2half(acc[ntl][r] * dv);
        }
    }
}

// ---- aggregate helpers ----
__device__ __forceinline__ float4 load4h(const float2* __restrict__ base, size_t idx) {
    float2 r = base[idx];
    union { float2 f2; __half2 h2[2]; } u;
    u.f2 = r;
    float2 a = __half22float2(u.h2[0]);
    float2 b = __half22float2(u.h2[1]);
    return make_float4(a.x, a.y, b.x, b.y);
}

// out = relu(dinv_i*(S) + b); WSRC: S = dinv_i*H[i] + sum dinv_s*H[s] (raw H),
// else S = H[i] + sum H[s] (rows pre-scaled).
template <int M, bool WSRC>
__device__ void agg_body(int bid, const __half* __restrict__ H,
                         const int* __restrict__ off_g, const int* __restrict__ csr,
                         const float* __restrict__ dinv_g, const float* __restrict__ b,
                         __half* __restrict__ out, int Nloc) {
    constexpr int L = M / 4, NPW = 64 / L;
    int lane = threadIdx.x & 63;
    int wave = threadIdx.x >> 6;
    int fq   = lane & (L - 1);
    int sub  = lane / L;
    int node = (bid * 4 + wave) * NPW + sub;
    if (node >= Nloc) return;
    const float2* H4 = (const float2*)H;
    int j0 = off_g[node], j1 = off_g[node + 1];
    float dvi = dinv_g[node];
    float4 acc = load4h(H4, (size_t)node * L + fq);  // self-loop
    if (WSRC) { acc.x *= dvi; acc.y *= dvi; acc.z *= dvi; acc.w *= dvi; }
    int j = j0;
    for (; j + 8 <= j1; j += 8) {
        int s0 = csr[j],     s1 = csr[j + 1], s2 = csr[j + 2], s3 = csr[j + 3];
        int s4 = csr[j + 4], s5 = csr[j + 5], s6 = csr[j + 6], s7 = csr[j + 7];
        float4 a0 = load4h(H4, (size_t)s0 * L + fq);
        float4 a1 = load4h(H4, (size_t)s1 * L + fq);
        float4 a2 = load4h(H4, (size_t)s2 * L + fq);
        float4 a3 = load4h(H4, (size_t)s3 * L + fq);
        float4 a4 = load4h(H4, (size_t)s4 * L + fq);
        float4 a5 = load4h(H4, (size_t)s5 * L + fq);
        float4 a6 = load4h(H4, (size_t)s6 * L + fq);
        float4 a7 = load4h(H4, (size_t)s7 * L + fq);
        if (WSRC) {
            float d0 = dinv_g[s0], d1 = dinv_g[s1], d2 = dinv_g[s2], d3 = dinv_g[s3];
            float d4 = dinv_g[s4], d5 = dinv_g[s5], d6 = dinv_g[s6], d7 = dinv_g[s7];
            acc.x += (d0*a0.x + d1*a1.x + d2*a2.x + d3*a3.x) + (d4*a4.x + d5*a5.x + d6*a6.x + d7*a7.x);
            acc.y += (d0*a0.y + d1*a1.y + d2*a2.y + d3*a3.y) + (d4*a4.y + d5*a5.y + d6*a6.y + d7*a7.y);
            acc.z += (d0*a0.z + d1*a1.z + d2*a2.z + d3*a3.z) + (d4*a4.z + d5*a5.z + d6*a6.z + d7*a7.z);
            acc.w += (d0*a0.w + d1*a1.w + d2*a2.w + d3*a3.w) + (d4*a4.w + d5*a5.w + d6*a6.w + d7*a7.w);
        } else {
            acc.x += (a0.x + a1.x + a2.x + a3.x) + (a4.x + a5.x + a6.x + a7.x);
            acc.y += (a0.y + a1.y + a2.y + a3.y) + (a4.y + a5.y + a6.y + a7.y);
            acc.z += (a0.z + a1.z + a2.z + a3.z) + (a4.z + a5.z + a6.z + a7.z);
            acc.w += (a0.w + a1.w + a2.w + a3.w) + (a4.w + a5.w + a6.w + a7.w);
        }
    }
    for (; j < j1; ++j) {
        int s = csr[j];
        float4 a = load4h(H4, (size_t)s * L + fq);
        float d = WSRC ? dinv_g[s] : 1.0f;
        acc.x += d * a.x; acc.y += d * a.y; acc.z += d * a.z; acc.w += d * a.w;
    }
    float4 bb = ((const float4*)b)[fq];
    float  vx = dvi * acc.x + bb.x;
    float  vy = dvi * acc.y + bb.y;
    float  vz = dvi * acc.z + bb.z;
    float  vw = dvi * acc.w + bb.w;
    union { float2 f2; __half2 h2[2]; } o;
    o.h2[0] = __floats2half2_rn(vx > 0.f ? vx : 0.f, vy > 0.f ? vy : 0.f);
    o.h2[1] = __floats2half2_rn(vz > 0.f ? vz : 0.f, vw > 0.f ? vw : 0.f);
    ((float2*)out)[(size_t)node * L + fq] = o.f2;
}

// ---- fused kernels ----
__global__ __launch_bounds__(256) void phaseA(const int* __restrict__ c_edge, int Ec,
                                              const int* __restrict__ s_edge, int Es,
                                              int Nc_pad, int Etot, int nbuck,
                                              int* __restrict__ bucket_fill, unsigned* __restrict__ pk,
                                              const float* __restrict__ c, const float* __restrict__ Wc0,
                                              __half* __restrict__ cH, int Nc,
                                              const float* __restrict__ s, const float* __restrict__ Ws0,
                                              __half* __restrict__ sH, int Ns,
                                              const float* __restrict__ Wc1, _Float16* __restrict__ wzC1,
                                              const float* __restrict__ Wc2, _Float16* __restrict__ wzC2,
                                              const float* __restrict__ Ws1, _Float16* __restrict__ wzS1,
                                              const float* __restrict__ Ws2, _Float16* __restrict__ wzS2,
                                              int nbP1, int nbGmC, int nbGmS) {
    __shared__ __align__(16) char smem[26624];
    int b = blockIdx.x;
    if (b < nbP1) { p1_body(b, c_edge, Ec, s_edge, Es, Nc_pad, Etot, nbuck, bucket_fill, pk, smem); return; }
    b -= nbP1;
    if (b < nbGmC) { gemm_mfma_f32<64, 64>(b, c, Wc0, nullptr, cH, Nc, smem); return; }
    b -= nbGmC;
    if (b < nbGmS) { gemm_mfma_f32<64, 32>(b, s, Ws0, nullptr, sH, Ns, smem); return; }
    b -= nbGmS;
    if (b == 0) prepW_body(Wc1, 64, wzC1);
    else if (b == 1) prepW_body(Wc2, 64, wzC2);
    else if (b == 2) prepW_body(Ws1, 32, wzS1);
    else             prepW_body(Ws2, 32, wzS2);
}

__global__ __launch_bounds__(256) void gemmDirectBoth(const __half* __restrict__ Xc, const _Float16* __restrict__ wzC,
                                                      __half* __restrict__ cH, int Nc,
                                                      const __half* __restrict__ Xs, const _Float16* __restrict__ wzS,
                                                      __half* __restrict__ sH, int Ns,
                                                      const float* __restrict__ dinv_all, int Nc_pad, int nbC) {
    if (blockIdx.x < nbC) gemm_direct<64>(blockIdx.x, Xc, wzC, dinv_all, cH, Nc);
    else                  gemm_direct<32>(blockIdx.x - nbC, Xs, wzS, dinv_all + Nc_pad, sH, Ns);
}

template <bool WSRC>
__global__ __launch_bounds__(256) void aggBoth(const __half* __restrict__ cH, const __half* __restrict__ sH,
                                               const int* __restrict__ off_all, const int* __restrict__ csr_all,
                                               const float* __restrict__ dinv_all,
                                               const float* __restrict__ bc, const float* __restrict__ bs,
                                               __half* __restrict__ outc, __half* __restrict__ outs,
                                               int Nc, int Ns, int Nc_pad, int nbC) {
    if (blockIdx.x < nbC)
        agg_body<64, WSRC>(blockIdx.x, cH, off_all, csr_all, dinv_all, bc, outc, Nc);
    else
        agg_body<32, WSRC>(blockIdx.x - nbC, sH, off_all + Nc_pad, csr_all,
                           dinv_all + Nc_pad, bs, outs, Ns);
}

// ---- fused pooling + MLP head ----
__device__ __forceinline__ int lbound(const int* __restrict__ a, int n, int key) {
    int lo = 0, hi = n;
    while (lo < hi) {
        int mid = (lo + hi) >> 1;
        if (a[mid] < key) lo = mid + 1; else hi = mid;
    }
    return lo;
}

__global__ __launch_bounds__(128) void poolDense(const __half* __restrict__ cX, const int* __restrict__ c_batch, int Nc,
                                                 const __half* __restrict__ sX, const int* __restrict__ s_batch, int Ns,
                                                 const float* __restrict__ Wd, const float* __restrict__ bd,
                                                 const float* __restrict__ Wo, const float* __restrict__ bo,
                                                 float* __restrict__ outv, float* __restrict__ embed) {
    __shared__ float e[192];
    __shared__ float red[128];
    int g = blockIdx.x, t = threadIdx.x;
    if (t < 64) {
        int lo = lbound(c_batch, Nc, g), hi = lbound(c_batch, Nc, g + 1);
        float mx = 0.f, sm = 0.f;
        for (int i = lo; i < hi; ++i) {
            float v = __half2float(cX[(size_t)i * 64 + t]);
            mx = fmaxf(mx, v); sm += v;
        }
        int cn = hi - lo;
        e[t]      = mx;
        e[64 + t] = sm / (float)(cn > 0 ? cn : 1);
    } else if (t < 96) {
        int f  = t - 64;
        int lo = lbound(s_batch, Ns, g), hi = lbound(s_batch, Ns, g + 1);
        float mx = 0.f, sm = 0.f;
        for (int i = lo; i < hi; ++i) {
            float v = __half2float(sX[(size_t)i * 32 + f]);
            mx = fmaxf(mx, v); sm += v;
        }
        int cn = hi - lo;
        e[128 + f] = mx;
        e[160 + f] = sm / (float)(cn > 0 ? cn : 1);
    }
    __syncthreads();
    for (int k = t; k < 192; k += 128) embed[(size_t)g * 192 + k] = e[k];
    float acc = bd[t];
    for (int k = 0; k < 192; ++k) acc += e[k] * Wd[k * 128 + t];
    float d = acc > 0.f ? acc : 0.f;
    red[t]  = d * Wo[t];
    __syncthreads();
    for (int ofs = 64; ofs > 0; ofs >>= 1) {
        if (t < ofs) red[t] += red[t + ofs];
        __syncthreads();
    }
    if (t == 0) outv[g] = red[0] + bo[0];
}

// ---------------------------------------------------------------------------

extern "C" void kernel_launch(void* const* d_in, const int* in_sizes, int n_in,
                              void* d_out, int out_size, void* d_ws, size_t ws_size,
                              hipStream_t stream) {
    const float* c       = (const float*)d_in[0];
    const int*   c_edge  = (const int*)d_in[1];
    const int*   c_batch = (const int*)d_in[2];
    const float* s       = (const float*)d_in[3];
    const int*   s_edge  = (const int*)d_in[4];
    const int*   s_batch = (const int*)d_in[5];
    const float* Wc0 = (const float*)d_in[6],  *bc0 = (const float*)d_in[7];
    const float* Wc1 = (const float*)d_in[8],  *bc1 = (const float*)d_in[9];
    const float* Wc2 = (const float*)d_in[10], *bc2 = (const float*)d_in[11];
    const float* Ws0 = (const float*)d_in[12], *bs0 = (const float*)d_in[13];
    const float* Ws1 = (const float*)d_in[14], *bs1 = (const float*)d_in[15];
    const float* Ws2 = (const float*)d_in[16], *bs2 = (const float*)d_in[17];
    const float* Wd  = (const float*)d_in[18], *bd  = (const float*)d_in[19];
    const float* Wo  = (const float*)d_in[20], *bo  = (const float*)d_in[21];

    const int Nc = in_sizes[0] / 64;
    const int Ec = in_sizes[1] / 2;
    const int Ns = in_sizes[3] / 64;
    const int Es = in_sizes[4] / 2;
    const int G  = out_size / 193;  // 2048
    const int Nc_pad   = cdiv(Nc, 512) * 512;
    const int Ns_pad   = cdiv(Ns, 512) * 512;
    const int Ntot_pad = Nc_pad + Ns_pad;
    const int Etot     = Ec + Es;
    const int nbuck    = Ntot_pad >> 9;

    // ---- workspace carve ----
    char* p = (char*)d_ws;
    auto  alloc = [&](size_t bytes) -> void* {
        void* r = (void*)p;
        p += (bytes + 255) & ~(size_t)255;
        return r;
    };
    int*      bucket_fill = (int*)alloc(512 * 4);
    int*      bucket_base = (int*)alloc(512 * 4);
    unsigned* pk          = (unsigned*)alloc((size_t)nbuck * BUCKET_CAP * 4);
    int*      off_all     = (int*)alloc(((size_t)Ntot_pad + 1) * 4);
    int*      csr_all     = (int*)alloc((size_t)Etot * 4);
    float*    dinv_all    = (float*)alloc((size_t)Ntot_pad * 4);
    _Float16* wzC1        = (_Float16*)alloc(4096 * 2);
    _Float16* wzC2        = (_Float16*)alloc(4096 * 2);
    _Float16* wzS1        = (_Float16*)alloc(1024 * 2);
    _Float16* wzS2        = (_Float16*)alloc(1024 * 2);
    __half*   bufC        = (__half*)alloc((size_t)Nc * 64 * 2);   // agg out / gemm in
    __half*   bufS        = (__half*)alloc((size_t)Ns * 32 * 2);
    __half*   cHa         = (__half*)alloc((size_t)Nc * 64 * 2);   // gemm out / agg in
    __half*   sHa         = (__half*)alloc((size_t)Ns * 32 * 2);

    float* outv  = (float*)d_out;  // [G]
    float* embed = outv + G;       // [G][192]

    const int nbP1  = cdiv(Etot, P1_CHUNK);
    const int nbGmC = cdiv(Nc, 64), nbGmS = cdiv(Ns, 64);
    const int nbAgC = Nc_pad / 16,  nbAgS = Ns_pad / 32;

    // 1) zero bucket fills
    zero_int<<<cdiv(nbuck, 256), 256, 0, stream>>>(bucket_fill, nbuck);
    // 2) phase A: edge partition || layer-0 GEMM (unscaled) || W pre-swizzle
    phaseA<<<nbP1 + nbGmC + nbGmS + 4, 256, 0, stream>>>(
        c_edge, Ec, s_edge, Es, Nc_pad, Etot, nbuck, bucket_fill, pk,
        c, Wc0, cHa, Nc, s, Ws0, sHa, Ns,
        Wc1, wzC1, Wc2, wzC2, Ws1, wzS1, Ws2, wzS2,
        nbP1, nbGmC, nbGmS);
    // 3) bucket scan, 4) CSR build (+dinv)
    p2_scanbuckets<<<1, 512, 0, stream>>>(bucket_fill, nbuck, bucket_base, off_all, Ntot_pad, Etot);
    p3_build<<<nbuck, 512, 0, stream>>>(pk, bucket_fill, bucket_base,
                                        off_all, dinv_all, csr_all);

    // 5) layer-0 aggregate (per-edge dinv[src] on raw H)
    aggBoth<true><<<nbAgC + nbAgS, 256, 0, stream>>>(cHa, sHa, off_all, csr_all, dinv_all,
                                                     bc0, bs0, bufC, bufS, Nc, Ns, Nc_pad, nbAgC);
    // 6) layer 1 (LDS-free MFMA, pre-swizzled W, dinv row-scale)
    gemmDirectBoth<<<nbGmC + nbGmS, 256, 0, stream>>>(bufC, wzC1, cHa, Nc, bufS, wzS1, sHa, Ns,
                                                      dinv_all, Nc_pad, nbGmC);
    aggBoth<false><<<nbAgC + nbAgS, 256, 0, stream>>>(cHa, sHa, off_all, csr_all, dinv_all,
                                                      bc1, bs1, bufC, bufS, Nc, Ns, Nc_pad, nbAgC);
    // 7) layer 2
    gemmDirectBoth<<<nbGmC + nbGmS, 256, 0, stream>>>(bufC, wzC2, cHa, Nc, bufS, wzS2, sHa, Ns,
                                                      dinv_all, Nc_pad, nbGmC);
    aggBoth<false><<<nbAgC + nbAgS, 256, 0, stream>>>(cHa, sHa, off_all, csr_all, dinv_all,
                                                      bc2, bs2, bufC, bufS, Nc, Ns, Nc_pad, nbAgC);

    // 8) fused pooling + MLP
    poolDense<<<G, 128, 0, stream>>>(bufC, c_batch, Nc, bufS, s_batch, Ns,
                                     Wd, bd, Wo, bo, outv, embed);
}

// Round 10
// 374.311 us; speedup vs baseline: 1.0402x; 1.0402x over previous
//
#include <hip/hip_runtime.h>
#include <hip/hip_fp16.h>
#include <math.h>

// ---------------------------------------------------------------------------
// SolventGCN round 10: r7 structure (best known: 367us) + two safe deltas:
//  * p2 folded into p3 (per-block local scan of bucket fills) — one less launch
//  * agg uses 16B (8-feature) lane loads: half the load/addr instructions at
//    equal bytes-in-flight. (r9's WSRC agg + direct-gemm reverted: +22us.)
//   zero -> p1 -> p3(+scan) -> gemmBoth0 -> 3x { aggBoth / gemmBoth }
//   -> poolDense.   10 launches.
// ---------------------------------------------------------------------------

static inline int cdiv(int a, int b) { return (a + b - 1) / b; }

#define BUCKET_CAP 8192
#define P1_CHUNK   4096

typedef _Float16 v8h __attribute__((ext_vector_type(8)));
typedef float    v4f __attribute__((ext_vector_type(4)));

__global__ void zero_int(int* __restrict__ p, int n) {
    int i = blockIdx.x * blockDim.x + threadIdx.x;
    if (i < n) p[i] = 0;
}

// ---- pass 1: partition edges into buckets (packed) ----
__global__ __launch_bounds__(256) void p1_partition(const int* __restrict__ c_edge, int Ec,
                                                    const int* __restrict__ s_edge, int Es,
                                                    int Nc_pad, int Etot, int nbuck,
                                                    int* __restrict__ bucket_fill,
                                                    unsigned* __restrict__ pk) {
    __shared__ unsigned       wbuf[P1_CHUNK];
    __shared__ unsigned short bbuf[P1_CHUNK];
    __shared__ int            hist[512];
    int e0 = blockIdx.x * P1_CHUNK;
    int n  = Etot - e0;
    if (n > P1_CHUNK) n = P1_CHUNK;
    for (int i = threadIdx.x; i < nbuck; i += 256) hist[i] = 0;
    __syncthreads();
    for (int i = threadIdx.x; i < n; i += 256) {
        int e = e0 + i, src, g;
        if (e < Ec) { src = c_edge[e]; g = c_edge[Ec + e]; }
        else        { int e2 = e - Ec; src = s_edge[e2]; g = Nc_pad + s_edge[Es + e2]; }
        int b   = g >> 9;
        wbuf[i] = ((unsigned)(g & 511) << 17) | (unsigned)src;
        bbuf[i] = (unsigned short)b;
        atomicAdd(&hist[b], 1);
    }
    __syncthreads();
    for (int i = threadIdx.x; i < nbuck; i += 256) {
        int h = hist[i];
        hist[i] = h ? atomicAdd(&bucket_fill[i], h) : 0;
    }
    __syncthreads();
    for (int i = threadIdx.x; i < n; i += 256) {
        int b    = bbuf[i];
        int slot = atomicAdd(&hist[b], 1);
        if (slot < BUCKET_CAP) pk[(size_t)b * BUCKET_CAP + slot] = wbuf[i];
    }
}

// ---- pass 3: per-bucket CSR build; bucket base via local scan (p2 folded in) ----
__global__ __launch_bounds__(512) void p3_build(const unsigned* __restrict__ pk,
                                                const int* __restrict__ fillarr,
                                                int nbuck, int Ntot_pad, int Etot,
                                                int* __restrict__ off_all,
                                                float* __restrict__ dinv,
                                                int* __restrict__ csr) {
    __shared__ int sh[512];
    int b = blockIdx.x, tid = threadIdx.x;

    // local exclusive-prefix scan of bucket fills -> base of this bucket
    int fv = (tid < nbuck) ? fillarr[tid] : 0;
    sh[tid] = fv;
    __syncthreads();
    for (int ofs = 1; ofs < 512; ofs <<= 1) {
        int t = (tid >= ofs) ? sh[tid - ofs] : 0;
        __syncthreads();
        sh[tid] += t;
        __syncthreads();
    }
    int fill_b = fillarr[b];
    int base   = sh[b] - fill_b;          // exclusive prefix
    if (b == 0 && tid == 0) off_all[Ntot_pad] = Etot;
    int fill = fill_b;
    if (fill > BUCKET_CAP) fill = BUCKET_CAP;
    const unsigned* reg = pk + (size_t)b * BUCKET_CAP;
    __syncthreads();

    // per-node degree count
    sh[tid] = 0;
    __syncthreads();
    for (int i = tid; i < fill; i += 512) atomicAdd(&sh[reg[i] >> 17], 1);
    __syncthreads();
    int cnt = sh[tid];
    for (int ofs = 1; ofs < 512; ofs <<= 1) {   // inclusive scan
        int t = (tid >= ofs) ? sh[tid - ofs] : 0;
        __syncthreads();
        sh[tid] += t;
        __syncthreads();
    }
    int excl = sh[tid] - cnt;
    int node = b * 512 + tid;             // padded-global id
    off_all[node] = base + excl;
    dinv[node]    = rsqrtf((float)(cnt + 1));   // +1 self-loop
    __syncthreads();
    sh[tid] = excl;   // cursor for CSR scatter
    __syncthreads();
    for (int i = tid; i < fill; i += 512) {
        unsigned w    = reg[i];
        int      slot = atomicAdd(&sh[w >> 17], 1);
        csr[base + slot] = (int)(w & 0x1FFFFu);
    }
}

// ---- MFMA GEMM body: H[N][M] = fp16((X @ W) * dinv[row]), X fp32 or fp16 ----
template <int K, int M, typename TIN>
__device__ void gemm_mfma(int bid, const TIN* __restrict__ X, const float* __restrict__ W,
                          const float* __restrict__ dinv, __half* __restrict__ H, int N,
                          char* smem_) {
    constexpr int RB = 64, KP = K + 8, NT = M / 16, KS = K / 32;
    _Float16* Xh = (_Float16*)smem_;           // [RB][KP]
    _Float16* Wz = Xh + RB * KP;               // [NT*KS*64][8]
    const int t    = threadIdx.x;
    const int row0 = bid * RB;

    constexpr int WENT = NT * KS * 64;
    for (int idx = t; idx < WENT; idx += 256) {
        int lane = idx & 63, rest = idx >> 6;
        int ks = rest % KS, ntl = rest / KS;
        int kbase = ks * 32 + (lane >> 4) * 8;
        int col   = ntl * 16 + (lane & 15);
        union { float4 f4; _Float16 h[8]; } u;
#pragma unroll
        for (int j = 0; j < 8; ++j) u.h[j] = (_Float16)W[(kbase + j) * M + col];
        *(float4*)(Wz + idx * 8) = u.f4;
    }
    if constexpr (sizeof(TIN) == 4) {
        constexpr int NI = RB * K / 4;
        for (int idx = t; idx < NI; idx += 256) {
            int row = idx / (K / 4), k4 = idx % (K / 4);
            int gr = row0 + row;
            float4 v = make_float4(0.f, 0.f, 0.f, 0.f);
            if (gr < N) v = *(const float4*)((const float*)X + (size_t)gr * K + k4 * 4);
            union { float2 f2; _Float16 h[4]; } u;
            u.h[0] = (_Float16)v.x; u.h[1] = (_Float16)v.y;
            u.h[2] = (_Float16)v.z; u.h[3] = (_Float16)v.w;
            *(float2*)(Xh + row * KP + k4 * 4) = u.f2;
        }
    } else {
        constexpr int NI = RB * K / 8;
        for (int idx = t; idx < NI; idx += 256) {
            int row = idx / (K / 8), k8 = idx % (K / 8);
            int gr = row0 + row;
            float4 v = make_float4(0.f, 0.f, 0.f, 0.f);
            if (gr < N) v = *(const float4*)((const __half*)X + (size_t)gr * K + k8 * 8);
            *(float4*)(Xh + row * KP + k8 * 8) = v;
        }
    }
    __syncthreads();

    const int wave = t >> 6, lane = t & 63;
    const int quad = lane >> 4, nl = lane & 15;
    const int rowA = wave * 16 + nl;

    v4f acc[NT];
#pragma unroll
    for (int i = 0; i < NT; ++i) acc[i] = (v4f){0.f, 0.f, 0.f, 0.f};
#pragma unroll
    for (int ks = 0; ks < KS; ++ks) {
        v8h a = *(const v8h*)(Xh + rowA * KP + ks * 32 + quad * 8);
#pragma unroll
        for (int ntl = 0; ntl < NT; ++ntl) {
            v8h b = *(const v8h*)(Wz + ((ntl * KS + ks) * 64 + lane) * 8);
            acc[ntl] = __builtin_amdgcn_mfma_f32_16x16x32_f16(a, b, acc[ntl], 0, 0, 0);
        }
    }
#pragma unroll
    for (int r = 0; r < 4; ++r) {
        int gr = row0 + wave * 16 + quad * 4 + r;
        if (gr < N) {
            float dv = dinv[gr];
#pragma unroll
            for (int ntl = 0; ntl < NT; ++ntl)
                H[(size_t)gr * M + ntl * 16 + nl] = __float2half(acc[ntl][r] * dv);
        }
    }
}

// ---- aggregate: 8 features (16B) per lane ----
__device__ __forceinline__ void cvt8h(float4 r, float4& lo, float4& hi) {
    union { float4 f4; __half2 h2[4]; } u;
    u.f4 = r;
    float2 p0 = __half22float2(u.h2[0]);
    float2 p1 = __half22float2(u.h2[1]);
    float2 p2 = __half22float2(u.h2[2]);
    float2 p3 = __half22float2(u.h2[3]);
    lo = make_float4(p0.x, p0.y, p1.x, p1.y);
    hi = make_float4(p2.x, p2.y, p3.x, p3.y);
}

__device__ __forceinline__ void add8(float4& alo, float4& ahi, float4 r4lo, float4 r4hi) {
    alo.x += r4lo.x; alo.y += r4lo.y; alo.z += r4lo.z; alo.w += r4lo.w;
    ahi.x += r4hi.x; ahi.y += r4hi.y; ahi.z += r4hi.z; ahi.w += r4hi.w;
}

template <int M>
__device__ void agg_body(int bid, const __half* __restrict__ H,
                         const int* __restrict__ off_g, const int* __restrict__ csr,
                         const float* __restrict__ dinv_g, const float* __restrict__ b,
                         __half* __restrict__ out, int Nloc) {
    constexpr int L = M / 8;     // lanes per node (8 halves = 16B each)
    constexpr int NPW = 64 / L;  // nodes per wave (c:8, s:16)
    int lane = threadIdx.x & 63;
    int wave = threadIdx.x >> 6;
    int fq   = lane & (L - 1);
    int sub  = lane / L;
    int node = (bid * 4 + wave) * NPW + sub;
    if (node >= Nloc) return;
    const float4* H8 = (const float4*)H;
    int j0 = off_g[node], j1 = off_g[node + 1];
    float4 alo, ahi;
    cvt8h(H8[(size_t)node * L + fq], alo, ahi);   // self-loop
    int j = j0;
    for (; j + 4 <= j1; j += 4) {
        int s0 = csr[j], s1 = csr[j + 1], s2 = csr[j + 2], s3 = csr[j + 3];
        float4 r0 = H8[(size_t)s0 * L + fq];
        float4 r1 = H8[(size_t)s1 * L + fq];
        float4 r2 = H8[(size_t)s2 * L + fq];
        float4 r3 = H8[(size_t)s3 * L + fq];
        float4 lo, hi;
        cvt8h(r0, lo, hi); add8(alo, ahi, lo, hi);
        cvt8h(r1, lo, hi); add8(alo, ahi, lo, hi);
        cvt8h(r2, lo, hi); add8(alo, ahi, lo, hi);
        cvt8h(r3, lo, hi); add8(alo, ahi, lo, hi);
    }
    for (; j < j1; ++j) {
        float4 lo, hi;
        cvt8h(H8[(size_t)csr[j] * L + fq], lo, hi);
        add8(alo, ahi, lo, hi);
    }
    float  dv  = dinv_g[node];
    const float4* b4 = (const float4*)b;
    float4 blo = b4[2 * fq], bhi = b4[2 * fq + 1];
    float v0 = fmaxf(dv * alo.x + blo.x, 0.f);
    float v1 = fmaxf(dv * alo.y + blo.y, 0.f);
    float v2 = fmaxf(dv * alo.z + blo.z, 0.f);
    float v3 = fmaxf(dv * alo.w + blo.w, 0.f);
    float v4 = fmaxf(dv * ahi.x + bhi.x, 0.f);
    float v5 = fmaxf(dv * ahi.y + bhi.y, 0.f);
    float v6 = fmaxf(dv * ahi.z + bhi.z, 0.f);
    float v7 = fmaxf(dv * ahi.w + bhi.w, 0.f);
    union { float4 f4; __half2 h2[4]; } o;
    o.h2[0] = __floats2half2_rn(v0, v1);
    o.h2[1] = __floats2half2_rn(v2, v3);
    o.h2[2] = __floats2half2_rn(v4, v5);
    o.h2[3] = __floats2half2_rn(v6, v7);
    ((float4*)out)[(size_t)node * L + fq] = o.f4;
}

// ---- fused two-side kernels ----
__global__ __launch_bounds__(256) void gemmBoth0(const float* __restrict__ Xc, const float* __restrict__ Wc,
                                                 __half* __restrict__ cH, int Nc,
                                                 const float* __restrict__ Xs, const float* __restrict__ Ws,
                                                 __half* __restrict__ sH, int Ns,
                                                 const float* __restrict__ dinv_all, int Nc_pad, int nbC) {
    __shared__ __align__(16) char smem[17408];
    if (blockIdx.x < nbC) gemm_mfma<64, 64, float>(blockIdx.x, Xc, Wc, dinv_all, cH, Nc, smem);
    else                  gemm_mfma<64, 32, float>(blockIdx.x - nbC, Xs, Ws, dinv_all + Nc_pad, sH, Ns, smem);
}

__global__ __launch_bounds__(256) void gemmBoth(const __half* __restrict__ Xc, const float* __restrict__ Wc,
                                                __half* __restrict__ cH, int Nc,
                                                const __half* __restrict__ Xs, const float* __restrict__ Ws,
                                                __half* __restrict__ sH, int Ns,
                                                const float* __restrict__ dinv_all, int Nc_pad, int nbC) {
    __shared__ __align__(16) char smem[17408];
    if (blockIdx.x < nbC) gemm_mfma<64, 64, __half>(blockIdx.x, Xc, Wc, dinv_all, cH, Nc, smem);
    else                  gemm_mfma<32, 32, __half>(blockIdx.x - nbC, Xs, Ws, dinv_all + Nc_pad, sH, Ns, smem);
}

__global__ __launch_bounds__(256) void aggBoth(const __half* __restrict__ cH, const __half* __restrict__ sH,
                                               const int* __restrict__ off_all, const int* __restrict__ csr_all,
                                               const float* __restrict__ dinv_all,
                                               const float* __restrict__ bc, const float* __restrict__ bs,
                                               __half* __restrict__ outc, __half* __restrict__ outs,
                                               int Nc, int Ns, int Nc_pad, int nbC) {
    if (blockIdx.x < nbC)
        agg_body<64>(blockIdx.x, cH, off_all, csr_all, dinv_all, bc, outc, Nc);
    else
        agg_body<32>(blockIdx.x - nbC, sH, off_all + Nc_pad, csr_all,
                     dinv_all + Nc_pad, bs, outs, Ns);
}

// ---- fused pooling + MLP head ----
__device__ __forceinline__ int lbound(const int* __restrict__ a, int n, int key) {
    int lo = 0, hi = n;
    while (lo < hi) {
        int mid = (lo + hi) >> 1;
        if (a[mid] < key) lo = mid + 1; else hi = mid;
    }
    return lo;
}

__global__ __launch_bounds__(128) void poolDense(const __half* __restrict__ cX, const int* __restrict__ c_batch, int Nc,
                                                 const __half* __restrict__ sX, const int* __restrict__ s_batch, int Ns,
                                                 const float* __restrict__ Wd, const float* __restrict__ bd,
                                                 const float* __restrict__ Wo, const float* __restrict__ bo,
                                                 float* __restrict__ outv, float* __restrict__ embed) {
    __shared__ float e[192];
    __shared__ float red[128];
    int g = blockIdx.x, t = threadIdx.x;
    if (t < 64) {
        int lo = lbound(c_batch, Nc, g), hi = lbound(c_batch, Nc, g + 1);
        float mx = 0.f, sm = 0.f;
        for (int i = lo; i < hi; ++i) {
            float v = __half2float(cX[(size_t)i * 64 + t]);
            mx = fmaxf(mx, v); sm += v;
        }
        int cn = hi - lo;
        e[t]      = mx;
        e[64 + t] = sm / (float)(cn > 0 ? cn : 1);
    } else if (t < 96) {
        int f  = t - 64;
        int lo = lbound(s_batch, Ns, g), hi = lbound(s_batch, Ns, g + 1);
        float mx = 0.f, sm = 0.f;
        for (int i = lo; i < hi; ++i) {
            float v = __half2float(sX[(size_t)i * 32 + f]);
            mx = fmaxf(mx, v); sm += v;
        }
        int cn = hi - lo;
        e[128 + f] = mx;
        e[160 + f] = sm / (float)(cn > 0 ? cn : 1);
    }
    __syncthreads();
    for (int k = t; k < 192; k += 128) embed[(size_t)g * 192 + k] = e[k];
    float acc = bd[t];
    for (int k = 0; k < 192; ++k) acc += e[k] * Wd[k * 128 + t];
    float d = acc > 0.f ? acc : 0.f;
    red[t]  = d * Wo[t];
    __syncthreads();
    for (int ofs = 64; ofs > 0; ofs >>= 1) {
        if (t < ofs) red[t] += red[t + ofs];
        __syncthreads();
    }
    if (t == 0) outv[g] = red[0] + bo[0];
}

// ---------------------------------------------------------------------------

extern "C" void kernel_launch(void* const* d_in, const int* in_sizes, int n_in,
                              void* d_out, int out_size, void* d_ws, size_t ws_size,
                              hipStream_t stream) {
    const float* c       = (const float*)d_in[0];
    const int*   c_edge  = (const int*)d_in[1];
    const int*   c_batch = (const int*)d_in[2];
    const float* s       = (const float*)d_in[3];
    const int*   s_edge  = (const int*)d_in[4];
    const int*   s_batch = (const int*)d_in[5];
    const float* Wc0 = (const float*)d_in[6],  *bc0 = (const float*)d_in[7];
    const float* Wc1 = (const float*)d_in[8],  *bc1 = (const float*)d_in[9];
    const float* Wc2 = (const float*)d_in[10], *bc2 = (const float*)d_in[11];
    const float* Ws0 = (const float*)d_in[12], *bs0 = (const float*)d_in[13];
    const float* Ws1 = (const float*)d_in[14], *bs1 = (const float*)d_in[15];
    const float* Ws2 = (const float*)d_in[16], *bs2 = (const float*)d_in[17];
    const float* Wd  = (const float*)d_in[18], *bd  = (const float*)d_in[19];
    const float* Wo  = (const float*)d_in[20], *bo  = (const float*)d_in[21];

    const int Nc = in_sizes[0] / 64;
    const int Ec = in_sizes[1] / 2;
    const int Ns = in_sizes[3] / 64;
    const int Es = in_sizes[4] / 2;
    const int G  = out_size / 193;  // 2048
    const int Nc_pad   = cdiv(Nc, 512) * 512;
    const int Ns_pad   = cdiv(Ns, 512) * 512;
    const int Ntot_pad = Nc_pad + Ns_pad;
    const int Etot     = Ec + Es;
    const int nbuck    = Ntot_pad >> 9;

    // ---- workspace carve ----
    char* p = (char*)d_ws;
    auto  alloc = [&](size_t bytes) -> void* {
        void* r = (void*)p;
        p += (bytes + 255) & ~(size_t)255;
        return r;
    };
    int*      bucket_fill = (int*)alloc(512 * 4);
    unsigned* pk          = (unsigned*)alloc((size_t)nbuck * BUCKET_CAP * 4);
    int*      off_all     = (int*)alloc(((size_t)Ntot_pad + 1) * 4);
    int*      csr_all     = (int*)alloc((size_t)Etot * 4);
    float*    dinv_all    = (float*)alloc((size_t)Ntot_pad * 4);
    __half*   bufC        = (__half*)alloc((size_t)Nc * 64 * 2);   // agg out / gemm in
    __half*   bufS        = (__half*)alloc((size_t)Ns * 32 * 2);
    __half*   cHa         = (__half*)alloc((size_t)Nc * 64 * 2);   // gemm out / agg in
    __half*   sHa         = (__half*)alloc((size_t)Ns * 32 * 2);

    float* outv  = (float*)d_out;  // [G]
    float* embed = outv + G;       // [G][192]

    const int nbGmC = cdiv(Nc, 64), nbGmS = cdiv(Ns, 64);
    const int nbAgC = Nc_pad / 32,  nbAgS = Ns_pad / 64;   // 8 / 16 nodes per wave

    // 1) CSR build (bucketed, LDS atomics only; p2 folded into p3)
    zero_int<<<cdiv(nbuck, 256), 256, 0, stream>>>(bucket_fill, nbuck);
    p1_partition<<<cdiv(Etot, P1_CHUNK), 256, 0, stream>>>(c_edge, Ec, s_edge, Es,
                                                           Nc_pad, Etot, nbuck, bucket_fill, pk);
    p3_build<<<nbuck, 512, 0, stream>>>(pk, bucket_fill, nbuck, Ntot_pad, Etot,
                                        off_all, dinv_all, csr_all);

    // 2) layer 0
    gemmBoth0<<<nbGmC + nbGmS, 256, 0, stream>>>(c, Wc0, cHa, Nc, s, Ws0, sHa, Ns,
                                                 dinv_all, Nc_pad, nbGmC);
    aggBoth<<<nbAgC + nbAgS, 256, 0, stream>>>(cHa, sHa, off_all, csr_all, dinv_all,
                                               bc0, bs0, bufC, bufS, Nc, Ns, Nc_pad, nbAgC);
    // 3) layer 1
    gemmBoth<<<nbGmC + nbGmS, 256, 0, stream>>>(bufC, Wc1, cHa, Nc, bufS, Ws1, sHa, Ns,
                                                dinv_all, Nc_pad, nbGmC);
    aggBoth<<<nbAgC + nbAgS, 256, 0, stream>>>(cHa, sHa, off_all, csr_all, dinv_all,
                                               bc1, bs1, bufC, bufS, Nc, Ns, Nc_pad, nbAgC);
    // 4) layer 2
    gemmBoth<<<nbGmC + nbGmS, 256, 0, stream>>>(bufC, Wc2, cHa, Nc, bufS, Ws2, sHa, Ns,
                                                dinv_all, Nc_pad, nbGmC);
    aggBoth<<<nbAgC + nbAgS, 256, 0, stream>>>(cHa, sHa, off_all, csr_all, dinv_all,
                                               bc2, bs2, bufC, bufS, Nc, Ns, Nc_pad, nbAgC);

    // 5) fused pooling + MLP
    poolDense<<<G, 128, 0, stream>>>(bufC, c_batch, Nc, bufS, s_batch, Ns,
                                     Wd, bd, Wo, bo, outv, embed);
}

// Round 11
// 369.524 us; speedup vs baseline: 1.0536x; 1.0130x over previous
//
#include <hip/hip_runtime.h>
#include <hip/hip_fp16.h>
#include <math.h>

// ---------------------------------------------------------------------------
// SolventGCN round 11: r7 verbatim (best: 367.6us; agg at 24 VGPR / 8B lanes)
// + gemm0 overlap: phaseA = p1_partition || UNSCALED layer-0 MFMA GEMM
//   (gemm0 has no CSR dependency), and the dinv row-scale is folded into
//   p3_build's tail (block owns its 512 rows + dinv in LDS; coalesced
//   in-place scale). 11 -> 10 launches, gemm0 off the critical path.
//   zero -> phaseA -> p2 -> p3(+scale) -> agg0 -> gemm1 -> agg1 -> gemm2
//   -> agg2 -> poolDense.
// ---------------------------------------------------------------------------

static inline int cdiv(int a, int b) { return (a + b - 1) / b; }

#define BUCKET_CAP 8192
#define P1_CHUNK   4096

typedef _Float16 v8h __attribute__((ext_vector_type(8)));
typedef float    v4f __attribute__((ext_vector_type(4)));

__global__ void zero_int(int* __restrict__ p, int n) {
    int i = blockIdx.x * blockDim.x + threadIdx.x;
    if (i < n) p[i] = 0;
}

// ---- p1 body: partition edges into buckets (packed) ----
__device__ void p1_body(int bid, const int* __restrict__ c_edge, int Ec,
                        const int* __restrict__ s_edge, int Es,
                        int Nc_pad, int Etot, int nbuck,
                        int* __restrict__ bucket_fill, unsigned* __restrict__ pk,
                        char* smem_) {
    unsigned*       wbuf = (unsigned*)smem_;                  // 16 KB
    unsigned short* bbuf = (unsigned short*)(smem_ + 16384);  // 8 KB
    int*            hist = (int*)(smem_ + 24576);             // 2 KB
    int e0 = bid * P1_CHUNK;
    int n  = Etot - e0;
    if (n > P1_CHUNK) n = P1_CHUNK;
    for (int i = threadIdx.x; i < nbuck; i += 256) hist[i] = 0;
    __syncthreads();
    for (int i = threadIdx.x; i < n; i += 256) {
        int e = e0 + i, src, g;
        if (e < Ec) { src = c_edge[e]; g = c_edge[Ec + e]; }
        else        { int e2 = e - Ec; src = s_edge[e2]; g = Nc_pad + s_edge[Es + e2]; }
        int b   = g >> 9;
        wbuf[i] = ((unsigned)(g & 511) << 17) | (unsigned)src;
        bbuf[i] = (unsigned short)b;
        atomicAdd(&hist[b], 1);
    }
    __syncthreads();
    for (int i = threadIdx.x; i < nbuck; i += 256) {
        int h = hist[i];
        hist[i] = h ? atomicAdd(&bucket_fill[i], h) : 0;
    }
    __syncthreads();
    for (int i = threadIdx.x; i < n; i += 256) {
        int b    = bbuf[i];
        int slot = atomicAdd(&hist[b], 1);
        if (slot < BUCKET_CAP) pk[(size_t)b * BUCKET_CAP + slot] = wbuf[i];
    }
}

// ---- pass 2: exclusive scan of bucket fills ----
__global__ __launch_bounds__(512) void p2_scanbuckets(const int* __restrict__ fill, int nbuck,
                                                      int* __restrict__ basearr,
                                                      int* __restrict__ off_all, int Ntot_pad, int Etot) {
    __shared__ int sh[512];
    int v = (threadIdx.x < nbuck) ? fill[threadIdx.x] : 0;
    sh[threadIdx.x] = v;
    __syncthreads();
    for (int ofs = 1; ofs < 512; ofs <<= 1) {
        int t = (threadIdx.x >= ofs) ? sh[threadIdx.x - ofs] : 0;
        __syncthreads();
        sh[threadIdx.x] += t;
        __syncthreads();
    }
    if (threadIdx.x < nbuck) basearr[threadIdx.x] = sh[threadIdx.x] - v;
    if (threadIdx.x == 0) off_all[Ntot_pad] = Etot;
}

// ---- pass 3: per-bucket CSR build + in-place dinv scale of layer-0 H ----
__global__ __launch_bounds__(512) void p3_build(const unsigned* __restrict__ pk,
                                                const int* __restrict__ fillarr,
                                                const int* __restrict__ basearr,
                                                int* __restrict__ off_all,
                                                float* __restrict__ dinv,
                                                int* __restrict__ csr,
                                                __half* __restrict__ cH, __half* __restrict__ sH,
                                                int Nc, int Ns, int Nc_pad, int nbuckC) {
    __shared__ int   sh[512];
    __shared__ float dls[512];
    int b    = blockIdx.x;
    int tid  = threadIdx.x;
    int fill = fillarr[b];
    if (fill > BUCKET_CAP) fill = BUCKET_CAP;
    int base = basearr[b];
    const unsigned* reg = pk + (size_t)b * BUCKET_CAP;
    sh[tid] = 0;
    __syncthreads();
    for (int i = tid; i < fill; i += 512) atomicAdd(&sh[reg[i] >> 17], 1);
    __syncthreads();
    int cnt = sh[tid];
    for (int ofs = 1; ofs < 512; ofs <<= 1) {   // inclusive scan
        int t = (tid >= ofs) ? sh[tid - ofs] : 0;
        __syncthreads();
        sh[tid] += t;
        __syncthreads();
    }
    int excl = sh[tid] - cnt;
    int node = b * 512 + tid;                   // padded-global id
    float dv = rsqrtf((float)(cnt + 1));        // +1 self-loop
    off_all[node] = base + excl;
    dinv[node]    = dv;
    dls[tid]      = dv;
    __syncthreads();
    sh[tid] = excl;   // cursor for CSR scatter
    __syncthreads();
    for (int i = tid; i < fill; i += 512) {
        unsigned w    = reg[i];
        int      slot = atomicAdd(&sh[w >> 17], 1);
        csr[base + slot] = (int)(w & 0x1FFFFu);
    }
    // in-place scale of layer-0 H rows owned by this bucket (dls synced above)
    if (b < nbuckC) {
        int rbase = b * 512;
        float4* H4 = (float4*)cH;               // 8 x 16B chunks per row
        for (int idx = tid; idx < 512 * 8; idx += 512) {
            int rl = idx >> 3, ch = idx & 7;
            int row = rbase + rl;
            if (row < Nc) {
                float d = dls[rl];
                union { float4 f4; __half2 h2[4]; } u;
                u.f4 = H4[(size_t)row * 8 + ch];
#pragma unroll
                for (int q = 0; q < 4; ++q) {
                    float2 p = __half22float2(u.h2[q]);
                    u.h2[q]  = __floats2half2_rn(p.x * d, p.y * d);
                }
                H4[(size_t)row * 8 + ch] = u.f4;
            }
        }
    } else {
        int rbase = b * 512 - Nc_pad;
        float4* H4 = (float4*)sH;               // 4 x 16B chunks per row
        for (int idx = tid; idx < 512 * 4; idx += 512) {
            int rl = idx >> 2, ch = idx & 3;
            int row = rbase + rl;
            if (row < Ns) {
                float d = dls[rl];
                union { float4 f4; __half2 h2[4]; } u;
                u.f4 = H4[(size_t)row * 4 + ch];
#pragma unroll
                for (int q = 0; q < 4; ++q) {
                    float2 p = __half22float2(u.h2[q]);
                    u.h2[q]  = __floats2half2_rn(p.x * d, p.y * d);
                }
                H4[(size_t)row * 4 + ch] = u.f4;
            }
        }
    }
}

// ---- MFMA GEMM body: H[N][M] = fp16((X @ W) * dinv?) , X fp32 or fp16 ----
template <int K, int M, typename TIN>
__device__ void gemm_mfma(int bid, const TIN* __restrict__ X, const float* __restrict__ W,
                          const float* __restrict__ dinv, __half* __restrict__ H, int N,
                          char* smem_) {
    constexpr int RB = 64, KP = K + 8, NT = M / 16, KS = K / 32;
    _Float16* Xh = (_Float16*)smem_;           // [RB][KP]
    _Float16* Wz = Xh + RB * KP;               // [NT*KS*64][8]
    const int t    = threadIdx.x;
    const int row0 = bid * RB;

    constexpr int WENT = NT * KS * 64;
    for (int idx = t; idx < WENT; idx += 256) {
        int lane = idx & 63, rest = idx >> 6;
        int ks = rest % KS, ntl = rest / KS;
        int kbase = ks * 32 + (lane >> 4) * 8;
        int col   = ntl * 16 + (lane & 15);
        union { float4 f4; _Float16 h[8]; } u;
#pragma unroll
        for (int j = 0; j < 8; ++j) u.h[j] = (_Float16)W[(kbase + j) * M + col];
        *(float4*)(Wz + idx * 8) = u.f4;
    }
    if constexpr (sizeof(TIN) == 4) {
        constexpr int NI = RB * K / 4;
        for (int idx = t; idx < NI; idx += 256) {
            int row = idx / (K / 4), k4 = idx % (K / 4);
            int gr = row0 + row;
            float4 v = make_float4(0.f, 0.f, 0.f, 0.f);
            if (gr < N) v = *(const float4*)((const float*)X + (size_t)gr * K + k4 * 4);
            union { float2 f2; _Float16 h[4]; } u;
            u.h[0] = (_Float16)v.x; u.h[1] = (_Float16)v.y;
            u.h[2] = (_Float16)v.z; u.h[3] = (_Float16)v.w;
            *(float2*)(Xh + row * KP + k4 * 4) = u.f2;
        }
    } else {
        constexpr int NI = RB * K / 8;
        for (int idx = t; idx < NI; idx += 256) {
            int row = idx / (K / 8), k8 = idx % (K / 8);
            int gr = row0 + row;
            float4 v = make_float4(0.f, 0.f, 0.f, 0.f);
            if (gr < N) v = *(const float4*)((const __half*)X + (size_t)gr * K + k8 * 8);
            *(float4*)(Xh + row * KP + k8 * 8) = v;
        }
    }
    __syncthreads();

    const int wave = t >> 6, lane = t & 63;
    const int quad = lane >> 4, nl = lane & 15;
    const int rowA = wave * 16 + nl;

    v4f acc[NT];
#pragma unroll
    for (int i = 0; i < NT; ++i) acc[i] = (v4f){0.f, 0.f, 0.f, 0.f};
#pragma unroll
    for (int ks = 0; ks < KS; ++ks) {
        v8h a = *(const v8h*)(Xh + rowA * KP + ks * 32 + quad * 8);
#pragma unroll
        for (int ntl = 0; ntl < NT; ++ntl) {
            v8h b = *(const v8h*)(Wz + ((ntl * KS + ks) * 64 + lane) * 8);
            acc[ntl] = __builtin_amdgcn_mfma_f32_16x16x32_f16(a, b, acc[ntl], 0, 0, 0);
        }
    }
#pragma unroll
    for (int r = 0; r < 4; ++r) {
        int gr = row0 + wave * 16 + quad * 4 + r;
        if (gr < N) {
            float dv = dinv ? dinv[gr] : 1.0f;
#pragma unroll
            for (int ntl = 0; ntl < NT; ++ntl)
                H[(size_t)gr * M + ntl * 16 + nl] = __float2half(acc[ntl][r] * dv);
        }
    }
}

// ---- aggregate: out = relu(dinv*(H[i]+sum H[src]) + b)  (r7 verbatim) ----
__device__ __forceinline__ float4 load4h(const float2* __restrict__ base, size_t idx) {
    float2 r = base[idx];
    union { float2 f2; __half2 h2[2]; } u;
    u.f2 = r;
    float2 a = __half22float2(u.h2[0]);
    float2 b = __half22float2(u.h2[1]);
    return make_float4(a.x, a.y, b.x, b.y);
}

template <int M>
__device__ void agg_body(int bid, const __half* __restrict__ H,
                         const int* __restrict__ off_g, const int* __restrict__ csr,
                         const float* __restrict__ dinv_g, const float* __restrict__ b,
                         __half* __restrict__ out, int Nloc) {
    constexpr int L = M / 4, NPW = 64 / L;
    int lane = threadIdx.x & 63;
    int wave = threadIdx.x >> 6;
    int fq   = lane & (L - 1);
    int sub  = lane / L;
    int node = (bid * 4 + wave) * NPW + sub;
    if (node >= Nloc) return;
    const float2* H4 = (const float2*)H;
    int j0 = off_g[node], j1 = off_g[node + 1];
    float4 acc = load4h(H4, (size_t)node * L + fq);  // self-loop
    int j = j0;
    for (; j + 8 <= j1; j += 8) {
        int s0 = csr[j],     s1 = csr[j + 1], s2 = csr[j + 2], s3 = csr[j + 3];
        int s4 = csr[j + 4], s5 = csr[j + 5], s6 = csr[j + 6], s7 = csr[j + 7];
        float4 a0 = load4h(H4, (size_t)s0 * L + fq);
        float4 a1 = load4h(H4, (size_t)s1 * L + fq);
        float4 a2 = load4h(H4, (size_t)s2 * L + fq);
        float4 a3 = load4h(H4, (size_t)s3 * L + fq);
        float4 a4 = load4h(H4, (size_t)s4 * L + fq);
        float4 a5 = load4h(H4, (size_t)s5 * L + fq);
        float4 a6 = load4h(H4, (size_t)s6 * L + fq);
        float4 a7 = load4h(H4, (size_t)s7 * L + fq);
        acc.x += (a0.x + a1.x + a2.x + a3.x) + (a4.x + a5.x + a6.x + a7.x);
        acc.y += (a0.y + a1.y + a2.y + a3.y) + (a4.y + a5.y + a6.y + a7.y);
        acc.z += (a0.z + a1.z + a2.z + a3.z) + (a4.z + a5.z + a6.z + a7.z);
        acc.w += (a0.w + a1.w + a2.w + a3.w) + (a4.w + a5.w + a6.w + a7.w);
    }
    for (; j + 4 <= j1; j += 4) {
        int s0 = csr[j], s1 = csr[j + 1], s2 = csr[j + 2], s3 = csr[j + 3];
        float4 a0 = load4h(H4, (size_t)s0 * L + fq);
        float4 a1 = load4h(H4, (size_t)s1 * L + fq);
        float4 a2 = load4h(H4, (size_t)s2 * L + fq);
        float4 a3 = load4h(H4, (size_t)s3 * L + fq);
        acc.x += a0.x + a1.x + a2.x + a3.x;
        acc.y += a0.y + a1.y + a2.y + a3.y;
        acc.z += a0.z + a1.z + a2.z + a3.z;
        acc.w += a0.w + a1.w + a2.w + a3.w;
    }
    for (; j < j1; ++j) {
        float4 a = load4h(H4, (size_t)csr[j] * L + fq);
        acc.x += a.x; acc.y += a.y; acc.z += a.z; acc.w += a.w;
    }
    float  dv = dinv_g[node];
    float4 bb = ((const float4*)b)[fq];
    float  vx = dv * acc.x + bb.x;
    float  vy = dv * acc.y + bb.y;
    float  vz = dv * acc.z + bb.z;
    float  vw = dv * acc.w + bb.w;
    union { float2 f2; __half2 h2[2]; } o;
    o.h2[0] = __floats2half2_rn(vx > 0.f ? vx : 0.f, vy > 0.f ? vy : 0.f);
    o.h2[1] = __floats2half2_rn(vz > 0.f ? vz : 0.f, vw > 0.f ? vw : 0.f);
    ((float2*)out)[(size_t)node * L + fq] = o.f2;
}

// ---- fused kernels ----
__global__ __launch_bounds__(256) void phaseA(const int* __restrict__ c_edge, int Ec,
                                              const int* __restrict__ s_edge, int Es,
                                              int Nc_pad, int Etot, int nbuck,
                                              int* __restrict__ bucket_fill, unsigned* __restrict__ pk,
                                              const float* __restrict__ c, const float* __restrict__ Wc0,
                                              __half* __restrict__ cH, int Nc,
                                              const float* __restrict__ s, const float* __restrict__ Ws0,
                                              __half* __restrict__ sH, int Ns,
                                              int nbP1, int nbGmC) {
    __shared__ __align__(16) char smem[26624];   // p1: 26KB; gemm<=17.4KB
    int b = blockIdx.x;
    if (b < nbP1) { p1_body(b, c_edge, Ec, s_edge, Es, Nc_pad, Etot, nbuck, bucket_fill, pk, smem); return; }
    b -= nbP1;
    if (b < nbGmC) { gemm_mfma<64, 64, float>(b, c, Wc0, nullptr, cH, Nc, smem); return; }
    b -= nbGmC;
    gemm_mfma<64, 32, float>(b, s, Ws0, nullptr, sH, Ns, smem);
}

__global__ __launch_bounds__(256) void gemmBoth(const __half* __restrict__ Xc, const float* __restrict__ Wc,
                                                __half* __restrict__ cH, int Nc,
                                                const __half* __restrict__ Xs, const float* __restrict__ Ws,
                                                __half* __restrict__ sH, int Ns,
                                                const float* __restrict__ dinv_all, int Nc_pad, int nbC) {
    __shared__ __align__(16) char smem[17408];
    if (blockIdx.x < nbC) gemm_mfma<64, 64, __half>(blockIdx.x, Xc, Wc, dinv_all, cH, Nc, smem);
    else                  gemm_mfma<32, 32, __half>(blockIdx.x - nbC, Xs, Ws, dinv_all + Nc_pad, sH, Ns, smem);
}

__global__ __launch_bounds__(256) void aggBoth(const __half* __restrict__ cH, const __half* __restrict__ sH,
                                               const int* __restrict__ off_all, const int* __restrict__ csr_all,
                                               const float* __restrict__ dinv_all,
                                               const float* __restrict__ bc, const float* __restrict__ bs,
                                               __half* __restrict__ outc, __half* __restrict__ outs,
                                               int Nc, int Ns, int Nc_pad, int nbC) {
    if (blockIdx.x < nbC)
        agg_body<64>(blockIdx.x, cH, off_all, csr_all, dinv_all, bc, outc, Nc);
    else
        agg_body<32>(blockIdx.x - nbC, sH, off_all + Nc_pad, csr_all,
                     dinv_all + Nc_pad, bs, outs, Ns);
}

// ---- fused pooling + MLP head ----
__device__ __forceinline__ int lbound(const int* __restrict__ a, int n, int key) {
    int lo = 0, hi = n;
    while (lo < hi) {
        int mid = (lo + hi) >> 1;
        if (a[mid] < key) lo = mid + 1; else hi = mid;
    }
    return lo;
}

__global__ __launch_bounds__(128) void poolDense(const __half* __restrict__ cX, const int* __restrict__ c_batch, int Nc,
                                                 const __half* __restrict__ sX, const int* __restrict__ s_batch, int Ns,
                                                 const float* __restrict__ Wd, const float* __restrict__ bd,
                                                 const float* __restrict__ Wo, const float* __restrict__ bo,
                                                 float* __restrict__ outv, float* __restrict__ embed) {
    __shared__ float e[192];
    __shared__ float red[128];
    int g = blockIdx.x, t = threadIdx.x;
    if (t < 64) {
        int lo = lbound(c_batch, Nc, g), hi = lbound(c_batch, Nc, g + 1);
        float mx = 0.f, sm = 0.f;
        for (int i = lo; i < hi; ++i) {
            float v = __half2float(cX[(size_t)i * 64 + t]);
            mx = fmaxf(mx, v); sm += v;
        }
        int cn = hi - lo;
        e[t]      = mx;
        e[64 + t] = sm / (float)(cn > 0 ? cn : 1);
    } else if (t < 96) {
        int f  = t - 64;
        int lo = lbound(s_batch, Ns, g), hi = lbound(s_batch, Ns, g + 1);
        float mx = 0.f, sm = 0.f;
        for (int i = lo; i < hi; ++i) {
            float v = __half2float(sX[(size_t)i * 32 + f]);
            mx = fmaxf(mx, v); sm += v;
        }
        int cn = hi - lo;
        e[128 + f] = mx;
        e[160 + f] = sm / (float)(cn > 0 ? cn : 1);
    }
    __syncthreads();
    for (int k = t; k < 192; k += 128) embed[(size_t)g * 192 + k] = e[k];
    float acc = bd[t];
    for (int k = 0; k < 192; ++k) acc += e[k] * Wd[k * 128 + t];
    float d = acc > 0.f ? acc : 0.f;
    red[t]  = d * Wo[t];
    __syncthreads();
    for (int ofs = 64; ofs > 0; ofs >>= 1) {
        if (t < ofs) red[t] += red[t + ofs];
        __syncthreads();
    }
    if (t == 0) outv[g] = red[0] + bo[0];
}

// ---------------------------------------------------------------------------

extern "C" void kernel_launch(void* const* d_in, const int* in_sizes, int n_in,
                              void* d_out, int out_size, void* d_ws, size_t ws_size,
                              hipStream_t stream) {
    const float* c       = (const float*)d_in[0];
    const int*   c_edge  = (const int*)d_in[1];
    const int*   c_batch = (const int*)d_in[2];
    const float* s       = (const float*)d_in[3];
    const int*   s_edge  = (const int*)d_in[4];
    const int*   s_batch = (const int*)d_in[5];
    const float* Wc0 = (const float*)d_in[6],  *bc0 = (const float*)d_in[7];
    const float* Wc1 = (const float*)d_in[8],  *bc1 = (const float*)d_in[9];
    const float* Wc2 = (const float*)d_in[10], *bc2 = (const float*)d_in[11];
    const float* Ws0 = (const float*)d_in[12], *bs0 = (const float*)d_in[13];
    const float* Ws1 = (const float*)d_in[14], *bs1 = (const float*)d_in[15];
    const float* Ws2 = (const float*)d_in[16], *bs2 = (const float*)d_in[17];
    const float* Wd  = (const float*)d_in[18], *bd  = (const float*)d_in[19];
    const float* Wo  = (const float*)d_in[20], *bo  = (const float*)d_in[21];

    const int Nc = in_sizes[0] / 64;
    const int Ec = in_sizes[1] / 2;
    const int Ns = in_sizes[3] / 64;
    const int Es = in_sizes[4] / 2;
    const int G  = out_size / 193;  // 2048
    const int Nc_pad   = cdiv(Nc, 512) * 512;
    const int Ns_pad   = cdiv(Ns, 512) * 512;
    const int Ntot_pad = Nc_pad + Ns_pad;
    const int Etot     = Ec + Es;
    const int nbuck    = Ntot_pad >> 9;
    const int nbuckC   = Nc_pad >> 9;

    // ---- workspace carve ----
    char* p = (char*)d_ws;
    auto  alloc = [&](size_t bytes) -> void* {
        void* r = (void*)p;
        p += (bytes + 255) & ~(size_t)255;
        return r;
    };
    int*      bucket_fill = (int*)alloc(512 * 4);
    int*      bucket_base = (int*)alloc(512 * 4);
    unsigned* pk          = (unsigned*)alloc((size_t)nbuck * BUCKET_CAP * 4);
    int*      off_all     = (int*)alloc(((size_t)Ntot_pad + 1) * 4);
    int*      csr_all     = (int*)alloc((size_t)Etot * 4);
    float*    dinv_all    = (float*)alloc((size_t)Ntot_pad * 4);
    __half*   bufC        = (__half*)alloc((size_t)Nc * 64 * 2);   // agg out / gemm in
    __half*   bufS        = (__half*)alloc((size_t)Ns * 32 * 2);
    __half*   cHa         = (__half*)alloc((size_t)Nc * 64 * 2);   // gemm out / agg in
    __half*   sHa         = (__half*)alloc((size_t)Ns * 32 * 2);

    float* outv  = (float*)d_out;  // [G]
    float* embed = outv + G;       // [G][192]

    const int nbP1  = cdiv(Etot, P1_CHUNK);
    const int nbGmC = cdiv(Nc, 64), nbGmS = cdiv(Ns, 64);
    const int nbAgC = Nc_pad / 16,  nbAgS = Ns_pad / 32;

    // 1) zero bucket fills
    zero_int<<<cdiv(nbuck, 256), 256, 0, stream>>>(bucket_fill, nbuck);
    // 2) phase A: edge partition || layer-0 GEMM (unscaled, no CSR dependency)
    phaseA<<<nbP1 + nbGmC + nbGmS, 256, 0, stream>>>(
        c_edge, Ec, s_edge, Es, Nc_pad, Etot, nbuck, bucket_fill, pk,
        c, Wc0, cHa, Nc, s, Ws0, sHa, Ns, nbP1, nbGmC);
    // 3) bucket scan; 4) CSR build + dinv + in-place H scale
    p2_scanbuckets<<<1, 512, 0, stream>>>(bucket_fill, nbuck, bucket_base, off_all, Ntot_pad, Etot);
    p3_build<<<nbuck, 512, 0, stream>>>(pk, bucket_fill, bucket_base,
                                        off_all, dinv_all, csr_all,
                                        cHa, sHa, Nc, Ns, Nc_pad, nbuckC);

    // 5) layer-0 aggregate
    aggBoth<<<nbAgC + nbAgS, 256, 0, stream>>>(cHa, sHa, off_all, csr_all, dinv_all,
                                               bc0, bs0, bufC, bufS, Nc, Ns, Nc_pad, nbAgC);
    // 6) layer 1
    gemmBoth<<<nbGmC + nbGmS, 256, 0, stream>>>(bufC, Wc1, cHa, Nc, bufS, Ws1, sHa, Ns,
                                                dinv_all, Nc_pad, nbGmC);
    aggBoth<<<nbAgC + nbAgS, 256, 0, stream>>>(cHa, sHa, off_all, csr_all, dinv_all,
                                               bc1, bs1, bufC, bufS, Nc, Ns, Nc_pad, nbAgC);
    // 7) layer 2
    gemmBoth<<<nbGmC + nbGmS, 256, 0, stream>>>(bufC, Wc2, cHa, Nc, bufS, Ws2, sHa, Ns,
                                                dinv_all, Nc_pad, nbGmC);
    aggBoth<<<nbAgC + nbAgS, 256, 0, stream>>>(cHa, sHa, off_all, csr_all, dinv_all,
                                               bc2, bs2, bufC, bufS, Nc, Ns, Nc_pad, nbAgC);

    // 8) fused pooling + MLP
    poolDense<<<G, 128, 0, stream>>>(bufC, c_batch, Nc, bufS, s_batch, Ns,
                                     Wd, bd, Wo, bo, outv, embed);
}